// Round 3
// baseline (405.321 us; speedup 1.0000x reference)
//
#include <hip/hip_runtime.h>

// RNN: B=4096, T=512, I=15, H=64, O=1
// Block = 256 threads = 4 waves, owns BPB=8 batch rows for all 512 steps
// (M=16 MFMA tile half-padded: trades 2x MFMA redundancy for 2 blocks/CU
//  = 2 waves/SIMD of TLP; we are latency-bound at MfmaUtil 12%).
// Per step: preact[16b][64j] = A[16][96] * Waug[96][64], A=[h|x_t|pad] in LDS
// (hi + lo-compensation for h), Waug in registers (hi+lo).
// Deep x-prefetch (D=8) + raw s_barrier WITHOUT vmcnt drain; 3 indep MFMA chains.

#define T_STEPS 512
#define I_DIM 15
#define BPB 8             // real batches per block (tile M=16, rows 8..15 pad)
#define TILEM 16
#define ROWSH 104         // LDS row stride in shorts; mult of 8 (b128 align)
#define DPF 8             // x prefetch depth (divides T_STEPS)

typedef __attribute__((ext_vector_type(8))) short short8;
typedef __attribute__((ext_vector_type(4))) float float4v;

__device__ __forceinline__ short f2bf_rne(float f) {
    union { float f; unsigned u; } v; v.f = f;
    unsigned r = (v.u + 0x7FFFu + ((v.u >> 16) & 1u)) >> 16;   // round-nearest-even
    return (short)r;
}
__device__ __forceinline__ float bf2f(short s) {
    union { float f; unsigned u; } v;
    v.u = ((unsigned)(unsigned short)s) << 16;
    return v.f;
}
__device__ __forceinline__ float fast_tanh(float x) {
    x = fminf(30.f, fmaxf(-30.f, x));
    float e = __builtin_exp2f(x * 2.8853900817779268f);  // e^(2x)
    return (e - 1.f) * __builtin_amdgcn_rcpf(e + 1.f);
}

__global__ __launch_bounds__(256) void rnn_fused(
    const float* __restrict__ x,     // [4096][512][15]
    const float* __restrict__ W_ih,  // [64][15]
    const float* __restrict__ W_hh,  // [64][64]
    const float* __restrict__ b_ih,  // [64]
    const float* __restrict__ b_hh,  // [64]
    const float* __restrict__ fc_w,  // [1][64]
    const float* __restrict__ fc_b,  // [1]
    float* __restrict__ out)         // [4096]
{
    __shared__ __align__(16) short Ahi[2][TILEM][ROWSH];
    __shared__ __align__(16) short Alo[2][TILEM][ROWSH];
    __shared__ float hfin[TILEM][65];

    const int tid  = threadIdx.x;
    const int wave = tid >> 6;
    const int lane = tid & 63;
    const int q    = lane >> 4;     // quad
    const int n    = lane & 15;     // A-row (batch) on read; C/D col (j) on write
    const int j    = wave * 16 + n; // hidden column this lane accumulates
    const int b0   = blockIdx.x * BPB;

    // zero LDS (h0 = 0; pad rows/columns start 0 in both buffers)
    for (int idx = tid; idx < 2 * TILEM * ROWSH; idx += 256) {
        ((short*)Ahi)[idx] = 0;
        ((short*)Alo)[idx] = 0;
    }

    // --- B fragments (Waug columns for this lane's j), hi+lo, in regs ---
    // value Waug[k][j], k = c*32 + q*8 + e
    short8 bhi[3], blo[3];
    for (int c = 0; c < 3; c++) {
        for (int e = 0; e < 8; e++) {
            int k = c * 32 + q * 8 + e;
            float w = 0.f;
            if (k < 64)       w = W_hh[j * 64 + k];
            else if (k < 79)  w = W_ih[j * 15 + (k - 64)];
            short hi = f2bf_rne(w);
            float rem = w - bf2f(hi);   // exact residual of hi
            bhi[c][e] = hi;
            blo[c][e] = f2bf_rne(rem);
        }
    }
    const float bias = b_ih[j] + b_hh[j];

    // x staging role: thread tid < BPB*15 handles x[b0+xb][*][xi]
    const int xb = tid / I_DIM, xi = tid - xb * I_DIM;
    const bool xactive = tid < BPB * I_DIM;
    const float* xrow = x + (size_t)(b0 + xb) * T_STEPS * I_DIM + xi;

    __syncthreads();   // zero-init visible before x(0) staging

    float xv[DPF];
    if (xactive) {
        // x(0) directly into buf 0
        float v0 = xrow[0];
        Ahi[0][xb][64 + xi] = f2bf_rne(v0);
        // preload pipeline: slot d%DPF holds x(d), d=1..DPF
        #pragma unroll
        for (int d = 1; d <= DPF; d++)
            xv[d & (DPF - 1)] = xrow[(size_t)d * I_DIM];
    }
    // raw barrier: LDS drained, global prefetch loads stay in flight
    asm volatile("s_waitcnt lgkmcnt(0)\n\ts_barrier" ::: "memory");

    float hreg[4] = {0.f, 0.f, 0.f, 0.f};

    for (int tb = 0; tb < T_STEPS / DPF; tb++) {
        #pragma unroll
        for (int u = 0; u < DPF; u++) {
            const int t  = tb * DPF + u;
            const int p  = u & 1, pn = p ^ 1;

            // A fragments: row m = n (batch), k = c*32 + q*8 + e
            const short* rowh = &Ahi[p][n][0];
            const short* rowl = &Alo[p][n][0];
            short8 ahi0 = *(const short8*)(rowh + 0 * 32 + q * 8);
            short8 ahi1 = *(const short8*)(rowh + 1 * 32 + q * 8);
            short8 ahi2 = *(const short8*)(rowh + 2 * 32 + q * 8);
            short8 alo0 = *(const short8*)(rowl + 0 * 32 + q * 8);
            short8 alo1 = *(const short8*)(rowl + 1 * 32 + q * 8);

            // stage x(t+1) into other buffer from the pipeline; refill slot
            if (xactive) {
                float v = xv[(u + 1) & (DPF - 1)];
                Ahi[pn][xb][64 + xi] = f2bf_rne(v);
                int tload = t + 1 + DPF;
                if (tload > T_STEPS - 1) tload = T_STEPS - 1;  // clamped dummy
                xv[(u + 1) & (DPF - 1)] = xrow[(size_t)tload * I_DIM];
            }

            // 3 independent accumulator chains (3 + 2 + 3 MFMAs)
            float4v acc0 = {0.f, 0.f, 0.f, 0.f};
            float4v acc1 = {0.f, 0.f, 0.f, 0.f};
            float4v acc2 = {0.f, 0.f, 0.f, 0.f};
            acc0 = __builtin_amdgcn_mfma_f32_16x16x32_bf16(ahi0, bhi[0], acc0, 0, 0, 0);
            acc1 = __builtin_amdgcn_mfma_f32_16x16x32_bf16(alo0, bhi[0], acc1, 0, 0, 0);
            acc2 = __builtin_amdgcn_mfma_f32_16x16x32_bf16(ahi0, blo[0], acc2, 0, 0, 0);
            acc0 = __builtin_amdgcn_mfma_f32_16x16x32_bf16(ahi1, bhi[1], acc0, 0, 0, 0);
            acc1 = __builtin_amdgcn_mfma_f32_16x16x32_bf16(alo1, bhi[1], acc1, 0, 0, 0);
            acc2 = __builtin_amdgcn_mfma_f32_16x16x32_bf16(ahi1, blo[1], acc2, 0, 0, 0);
            acc0 = __builtin_amdgcn_mfma_f32_16x16x32_bf16(ahi2, bhi[2], acc0, 0, 0, 0);
            acc2 = __builtin_amdgcn_mfma_f32_16x16x32_bf16(ahi2, blo[2], acc2, 0, 0, 0);

            // epilogue: bias + tanh, truncation split (lo compensates hi exactly)
            // C/D layout: col = lane&15 -> j, row = q*4 + r -> local batch.
            // Pad rows (brow >= BPB) compute finite garbage; MFMA row
            // independence keeps it out of real rows, so no gating needed.
            #pragma unroll
            for (int r = 0; r < 4; r++) {
                float pre = (acc0[r] + acc1[r]) + (acc2[r] + bias);
                float h = fast_tanh(pre);
                hreg[r] = h;
                const int brow = q * 4 + r;
                union { float f; unsigned uu; } hv; hv.f = h;
                short hi = (short)(hv.uu >> 16);           // truncate
                union { float f; unsigned uu; } hb; hb.uu = hv.uu & 0xFFFF0000u;
                float rem = h - hb.f;                       // exact residual
                union { float f; unsigned uu; } rv; rv.f = rem;
                short lo = (short)(rv.uu >> 16);            // truncate (2^-16 rel)
                Ahi[pn][brow][j] = hi;
                Alo[pn][brow][j] = lo;
            }
            // raw barrier: only LDS drained; x prefetch stays outstanding
            asm volatile("s_waitcnt lgkmcnt(0)\n\ts_barrier" ::: "memory");
        }
    }

    // final head: out[b] = sum_j h[b][j] * fc_w[j] + fc_b
    #pragma unroll
    for (int r = 0; r < 4; r++) hfin[q * 4 + r][j] = hreg[r];
    __syncthreads();
    if (tid < BPB) {
        float s = fc_b[0];
        for (int k = 0; k < 64; k++) s += hfin[tid][k] * fc_w[k];
        out[b0 + tid] = s;
    }
}

extern "C" void kernel_launch(void* const* d_in, const int* in_sizes, int n_in,
                              void* d_out, int out_size, void* d_ws, size_t ws_size,
                              hipStream_t stream) {
    const float* x    = (const float*)d_in[0];
    const float* W_ih = (const float*)d_in[1];
    const float* W_hh = (const float*)d_in[2];
    const float* b_ih = (const float*)d_in[3];
    const float* b_hh = (const float*)d_in[4];
    const float* fc_w = (const float*)d_in[5];
    const float* fc_b = (const float*)d_in[6];
    float* out = (float*)d_out;

    rnn_fused<<<4096 / BPB, 256, 0, stream>>>(x, W_ih, W_hh, b_ih, b_hh, fc_w, fc_b, out);
}

// Round 4
// 362.687 us; speedup vs baseline: 1.1175x; 1.1175x over previous
//
#include <hip/hip_runtime.h>

// RNN: B=4096, T=512, I=15, H=64, O=1
// Block = 256 threads = 4 waves, owns 16 batch rows for all 512 steps.
// R3: SWAPPED MFMA operands: preact^T[64j][16b] = Waug^T * A^T.
//   A-operand = Waug columns (registers, identical content to old B-frags)
//   B-operand = [h | x_t | pad] rows from LDS (identical reads to old A-frags)
//   C/D: row=q*4+r -> j_local, col=lane&15 -> batch  => h-write is a
//   row-contiguous ds_write_b64 (was 8x conflicted b16 column writes).
// hi+lo compensation for h (truncation split); W hi+lo (lo only k<64).
// Deep x-prefetch (D=8) + raw s_barrier without vmcnt drain.

#define T_STEPS 512
#define I_DIM 15
#define BPB 16            // batches per block
#define ROWSH 104         // LDS row stride in shorts (>=96 for K; 16B-aligned rows)
#define DPF 8             // x prefetch depth

typedef __attribute__((ext_vector_type(8))) short short8;
typedef __attribute__((ext_vector_type(4))) float float4v;

__device__ __forceinline__ short f2bf_rne(float f) {
    union { float f; unsigned u; } v; v.f = f;
    unsigned r = (v.u + 0x7FFFu + ((v.u >> 16) & 1u)) >> 16;
    return (short)r;
}
__device__ __forceinline__ float bf2f(short s) {
    union { float f; unsigned u; } v;
    v.u = ((unsigned)(unsigned short)s) << 16;
    return v.f;
}

__global__ __launch_bounds__(256) void rnn_fused(
    const float* __restrict__ x,     // [4096][512][15]
    const float* __restrict__ W_ih,  // [64][15]
    const float* __restrict__ W_hh,  // [64][64]
    const float* __restrict__ b_ih,  // [64]
    const float* __restrict__ b_hh,  // [64]
    const float* __restrict__ fc_w,  // [1][64]
    const float* __restrict__ fc_b,  // [1]
    float* __restrict__ out)         // [4096]
{
    __shared__ __align__(16) short Ahi[2][BPB][ROWSH];
    __shared__ __align__(16) short Alo[2][BPB][ROWSH];

    const int tid  = threadIdx.x;
    const int wave = tid >> 6;
    const int lane = tid & 63;
    const int q    = lane >> 4;
    const int n    = lane & 15;       // weight col j_w on A-frag; batch on C/D
    const int jw   = wave * 16 + n;   // weight column this lane supplies
    const int wj0  = wave * 16 + q * 4;  // first j this lane OUTPUTS (j = wj0+r)
    const int b0   = blockIdx.x * BPB;

    // zero LDS (h0 = 0; pad cols 79..95 must stay 0 in both buffers)
    for (int idx = tid; idx < 2 * BPB * ROWSH; idx += 256) {
        ((short*)Ahi)[idx] = 0;
        ((short*)Alo)[idx] = 0;
    }

    // --- A-operand fragments: Waug[k][jw], k = c*32 + q*8 + e ---
    short8 whi[3], wlo[2];
    for (int c = 0; c < 3; c++) {
        for (int e = 0; e < 8; e++) {
            int k = c * 32 + q * 8 + e;
            float w = 0.f;
            if (k < 64)       w = W_hh[jw * 64 + k];
            else if (k < 79)  w = W_ih[jw * 15 + (k - 64)];
            short hi = f2bf_rne(w);
            whi[c][e] = hi;
            if (c < 2) wlo[c][e] = f2bf_rne(w - bf2f(hi));  // W lo only for k<64
        }
    }
    // bias per OUTPUT row r (j = wj0 + r)
    float bias_r[4];
    #pragma unroll
    for (int r = 0; r < 4; r++) bias_r[r] = b_ih[wj0 + r] + b_hh[wj0 + r];

    // x staging: thread tid<240 handles x[b0+xb][*][xi]
    const int xb = tid / I_DIM, xi = tid - xb * I_DIM;
    const bool xactive = tid < BPB * I_DIM;
    const float* xrow = x + (size_t)(b0 + xb) * T_STEPS * I_DIM + xi;

    asm volatile("s_waitcnt lgkmcnt(0)\n\ts_barrier" ::: "memory");  // zeros visible

    float xv[DPF];
    if (xactive) {
        float v0 = xrow[0];
        Ahi[0][xb][64 + xi] = f2bf_rne(v0);
        #pragma unroll
        for (int d = 1; d <= DPF; d++)
            xv[d & (DPF - 1)] = xrow[(size_t)d * I_DIM];
    }
    asm volatile("s_waitcnt lgkmcnt(0)\n\ts_barrier" ::: "memory");

    for (int tb = 0; tb < T_STEPS / DPF; tb++) {
        #pragma unroll
        for (int u = 0; u < DPF; u++) {
            const int t  = tb * DPF + u;
            const int p  = u & 1, pn = p ^ 1;

            // B-operand fragments: h/x rows, B[k][batch=n], k = c*32+q*8+e
            const short* rowh = &Ahi[p][n][0];
            const short* rowl = &Alo[p][n][0];
            short8 hhi0 = *(const short8*)(rowh + 0 * 32 + q * 8);
            short8 hhi1 = *(const short8*)(rowh + 1 * 32 + q * 8);
            short8 hhi2 = *(const short8*)(rowh + 2 * 32 + q * 8);
            short8 hlo0 = *(const short8*)(rowl + 0 * 32 + q * 8);
            short8 hlo1 = *(const short8*)(rowl + 1 * 32 + q * 8);

            // stage x(t+1) into other buffer; refill pipeline slot
            if (xactive) {
                float v = xv[(u + 1) & (DPF - 1)];
                Ahi[pn][xb][64 + xi] = f2bf_rne(v);
                int tload = t + 1 + DPF;
                if (tload > T_STEPS - 1) tload = T_STEPS - 1;
                xv[(u + 1) & (DPF - 1)] = xrow[(size_t)tload * I_DIM];
            }

            // 3 independent chains: Whi*hhi (3), Whi*hlo (2), Wlo*hhi (2)
            float4v acc0 = {0.f, 0.f, 0.f, 0.f};
            float4v acc1 = {0.f, 0.f, 0.f, 0.f};
            float4v acc2 = {0.f, 0.f, 0.f, 0.f};
            acc0 = __builtin_amdgcn_mfma_f32_16x16x32_bf16(whi[0], hhi0, acc0, 0, 0, 0);
            acc1 = __builtin_amdgcn_mfma_f32_16x16x32_bf16(whi[0], hlo0, acc1, 0, 0, 0);
            acc2 = __builtin_amdgcn_mfma_f32_16x16x32_bf16(wlo[0], hhi0, acc2, 0, 0, 0);
            acc0 = __builtin_amdgcn_mfma_f32_16x16x32_bf16(whi[1], hhi1, acc0, 0, 0, 0);
            acc1 = __builtin_amdgcn_mfma_f32_16x16x32_bf16(whi[1], hlo1, acc1, 0, 0, 0);
            acc2 = __builtin_amdgcn_mfma_f32_16x16x32_bf16(wlo[1], hhi1, acc2, 0, 0, 0);
            acc0 = __builtin_amdgcn_mfma_f32_16x16x32_bf16(whi[2], hhi2, acc0, 0, 0, 0);

            // epilogue: D[row=q*4+r -> j=wj0+r][col=n -> batch n]
            // tanh(x) = 1 - 2/(exp2(2x/ln2)+1); |pre|<=~20 so no clamp needed
            unsigned hu[4], lu[4];
            #pragma unroll
            for (int r = 0; r < 4; r++) {
                float pre = (acc0[r] + acc1[r]) + (acc2[r] + bias_r[r]);
                float e = __builtin_exp2f(pre * 2.8853900817779268f);
                float h = 1.f - 2.f * __builtin_amdgcn_rcpf(e + 1.f);
                union { float f; unsigned u; } hv; hv.f = h;
                hu[r] = hv.u;
                union { float f; unsigned u; } hb; hb.u = hv.u & 0xFFFF0000u;
                union { float f; unsigned u; } rv; rv.f = h - hb.f;
                lu[r] = rv.u;
            }
            // pack 4 shorts -> one b64 write each for hi and lo
            uint2 hiv, lov;
            hiv.x = (hu[0] >> 16) | (hu[1] & 0xFFFF0000u);
            hiv.y = (hu[2] >> 16) | (hu[3] & 0xFFFF0000u);
            lov.x = (lu[0] >> 16) | (lu[1] & 0xFFFF0000u);
            lov.y = (lu[2] >> 16) | (lu[3] & 0xFFFF0000u);
            *(uint2*)&Ahi[pn][n][wj0] = hiv;
            *(uint2*)&Alo[pn][n][wj0] = lov;

            asm volatile("s_waitcnt lgkmcnt(0)\n\ts_barrier" ::: "memory");
        }
    }

    // final head: h(T-1) lives in buffer 0 (T=512 even); read hi+lo from LDS
    if (tid < BPB) {
        float s = fc_b[0];
        for (int k = 0; k < 64; k++) {
            float hv = bf2f(Ahi[0][tid][k]) + bf2f(Alo[0][tid][k]);
            s += hv * fc_w[k];
        }
        out[b0 + tid] = s;
    }
}

extern "C" void kernel_launch(void* const* d_in, const int* in_sizes, int n_in,
                              void* d_out, int out_size, void* d_ws, size_t ws_size,
                              hipStream_t stream) {
    const float* x    = (const float*)d_in[0];
    const float* W_ih = (const float*)d_in[1];
    const float* W_hh = (const float*)d_in[2];
    const float* b_ih = (const float*)d_in[3];
    const float* b_hh = (const float*)d_in[4];
    const float* fc_w = (const float*)d_in[5];
    const float* fc_b = (const float*)d_in[6];
    float* out = (float*)d_out;

    rnn_fused<<<4096 / BPB, 256, 0, stream>>>(x, W_ih, W_hh, b_ih, b_hh, fc_w, fc_b, out);
}